// Round 13
// baseline (821.469 us; speedup 1.0000x reference)
//
#include <hip/hip_runtime.h>
#include <stdint.h>

#define D 128
#define NACT 16
#define LAYERS 3
#define SCH 8192

typedef __attribute__((ext_vector_type(4))) float f32x4;
typedef __attribute__((ext_vector_type(8))) short short8;

__device__ __forceinline__ unsigned short f2bf(float f) {
  union { float f; unsigned int u; } v; v.f = f;
  return (unsigned short)((v.u + 0x7fffu + ((v.u >> 16) & 1u)) >> 16);
}
__device__ __forceinline__ float bf2f(unsigned short s) {
  union { unsigned int u; float f; } v; v.u = ((unsigned int)s) << 16; return v.f;
}
__device__ __forceinline__ f32x4 mfma16(short8 a, short8 b, f32x4 c) {
  return __builtin_amdgcn_mfma_f32_16x16x32_bf16(a, b, c, 0, 0, 0);
}
// XOR swizzle: byte offset within a 16-row x 256B LDS tile
__device__ __forceinline__ int SWZ(int row, int byteoff) {
  return (row * 256 + byteoff) ^ ((row & 7) << 4);
}

// Barrier that does NOT drain vmcnt (lgkm-only): keeps T14 stage loads in
// flight across the barrier. sched_barrier(0) fences compiler reordering.
__device__ __forceinline__ void wave_barrier_lds() {
  asm volatile("s_waitcnt lgkmcnt(0)" ::: "memory");
  __builtin_amdgcn_s_barrier();
  __builtin_amdgcn_sched_barrier(0);
}

__device__ __forceinline__ void accum_edge(unsigned w, unsigned t,
                                           float e00, float e01, float e10, float e11,
                                           float e20, float e21, float& a0, float& a1) {
  float ee0 = (t == 0) ? e00 : ((t == 1) ? e10 : e20);
  float ee1 = (t == 0) ? e01 : ((t == 1) ? e11 : e21);
  float v0 = bf2f((unsigned short)(w & 0xFFFF)) + ee0;
  float v1 = bf2f((unsigned short)(w >> 16)) + ee1;
  a0 += v0 > 0.f ? v0 : 0.f;
  a1 += v1 > 0.f ? v1 : 0.f;
}

// ---------------- mask dtype detection ----------------
__global__ void k_detect(const unsigned int* __restrict__ m, int nWords, int* __restrict__ flag) {
  int f = 0;
  for (int i = blockIdx.x * blockDim.x + threadIdx.x; i < nWords; i += gridDim.x * blockDim.x) {
    unsigned int w = m[i];
    if (w > 1u) f |= 1;
    if (w > 0x01010101u) f |= 2;
  }
  if (f) atomicOr(flag, f);
}

// ---------------- weight pack (transpose): dst[l][n][k] = bf16(src[l][k][n]) ----------------
__global__ void k_pack(const float* __restrict__ src, unsigned short* __restrict__ dst,
                       int Lc, int K, int N) {
  int total = Lc * K * N;
  for (int i = blockIdx.x * blockDim.x + threadIdx.x; i < total; i += gridDim.x * blockDim.x) {
    int l = i / (K * N);
    int rem = i - l * (K * N);
    int n = rem / K;
    int k = rem - n * K;
    dst[i] = f2bf(src[(l * K + k) * N + n]);
  }
}

// ---------------- row-major cast pack ----------------
__global__ void k_packrm(const float* __restrict__ src, unsigned short* __restrict__ dst, int n) {
  for (int i = blockIdx.x * blockDim.x + threadIdx.x; i < n; i += gridDim.x * blockDim.x)
    dst[i] = f2bf(src[i]);
}

// ---------------- eW tables: eW[l][dir][t][c] = sum_k eemb[t][k] * W[l][k][c] ----------------
__global__ void k_ew(const float* __restrict__ eemb, const float* __restrict__ Wvf,
                     const float* __restrict__ Wfv, float* __restrict__ eW) {
  int o = blockIdx.x * blockDim.x + threadIdx.x;
  if (o >= LAYERS * 2 * 3 * D) return;
  int c = o & 127;
  int r = o >> 7;
  int t = r % 3; r /= 3;
  int dir = r & 1;
  int l = r >> 1;
  const float* W = (dir == 0 ? Wvf : Wfv) + (size_t)l * D * D;
  float s = 0.f;
  for (int k = 0; k < D; ++k) s += eemb[t * D + k] * W[k * D + c];
  eW[o] = s;
}

// ---------------- CSR build ----------------
__global__ void k_hist(const int* __restrict__ dst, int n, int dadd, int* __restrict__ off) {
  for (int e = blockIdx.x * blockDim.x + threadIdx.x; e < n; e += gridDim.x * blockDim.x)
    atomicAdd(&off[dst[e] + dadd], 1);
}

__global__ void k_scan_sums(const int* __restrict__ data, int n, int* __restrict__ bsum) {
  __shared__ int ts[256];
  int base = blockIdx.x * SCH;
  int s = 0;
  for (int j = threadIdx.x; j < SCH; j += 256) {
    int i = base + j;
    if (i < n) s += data[i];
  }
  ts[threadIdx.x] = s;
  __syncthreads();
  if (threadIdx.x == 0) {
    int tot = 0;
    for (int i = 0; i < 256; ++i) tot += ts[i];
    bsum[blockIdx.x] = tot;
  }
}

__global__ void k_scan_top(int* __restrict__ bsum, int nb) {
  if (threadIdx.x == 0 && blockIdx.x == 0) {
    int run = 0;
    for (int i = 0; i < nb; ++i) { int t = bsum[i]; bsum[i] = run; run += t; }
  }
}

__global__ void k_scan_apply(int* __restrict__ data, int n, const int* __restrict__ bsum) {
  __shared__ int ts[256];
  int base = blockIdx.x * SCH + threadIdx.x * 32;
  int v[32];
  int s = 0;
#pragma unroll
  for (int j = 0; j < 32; ++j) {
    int i = base + j;
    v[j] = (i < n) ? data[i] : 0;
    s += v[j];
  }
  ts[threadIdx.x] = s;
  __syncthreads();
  if (threadIdx.x == 0) {
    int run = 0;
    for (int i = 0; i < 256; ++i) { int t = ts[i]; ts[i] = run; run += t; }
  }
  __syncthreads();
  int run = bsum[blockIdx.x] + ts[threadIdx.x];
#pragma unroll
  for (int j = 0; j < 32; ++j) {
    run += v[j];
    int i = base + j;
    if (i < n) data[i] = run;  // inclusive scan
  }
}

__global__ void k_set1(int* __restrict__ p, int v) {
  if (threadIdx.x == 0 && blockIdx.x == 0) *p = v;
}

__global__ void k_scatter(const int* __restrict__ dst, const int* __restrict__ src,
                          const int* __restrict__ ety, int n, int dadd, int sadd,
                          int* __restrict__ off, unsigned* __restrict__ pk) {
  for (int e = blockIdx.x * blockDim.x + threadIdx.x; e < n; e += gridDim.x * blockDim.x) {
    int d = dst[e] + dadd;
    int pos = atomicAdd(&off[d], -1) - 1;
    pk[pos] = (unsigned)(src[e] + sadd) | ((unsigned)ety[e] << 20);
  }
}

// ---------------- fused: variable embedding + xW_v(l=0) ----------------
__global__ void __launch_bounds__(256)
k_emb_xw(const int* __restrict__ vtb, const int* __restrict__ vvb,
         const int* __restrict__ vtn, const float* __restrict__ vvn,
         const float* __restrict__ pred, const float* __restrict__ bemb,
         const float* __restrict__ numw, const float* __restrict__ numb,
         const unsigned short* __restrict__ WxT,
         unsigned short* __restrict__ vars, unsigned short* __restrict__ xw,
         int nvb, int nv) {
  __shared__ unsigned short LDSO[64 * 128];
  __shared__ unsigned short LDSA[64 * 128];
  int wid = threadIdx.x >> 6, lane = threadIdx.x & 63;
  int r16 = lane & 15, g = lane >> 4;
  int rbase = blockIdx.x * 64 + wid * 16;
  char* ldso = (char*)LDSO + wid * 16 * 256;
  char* ldsa = (char*)LDSA + wid * 16 * 256;
  int c2 = lane * 2;

  for (int r = 0; r < 16; ++r) {
    int row = rbase + r;
    int rg = row < nv ? row : nv - 1;
    float x0, x1;
    if (rg < nvb) {
      int tp = vtb[rg], bv = vvb[rg];
      x0 = pred[tp * D + c2] + bemb[bv * D + c2];
      x1 = pred[tp * D + c2 + 1] + bemb[bv * D + c2 + 1];
    } else {
      int j = rg - nvb;
      int tp = vtn[j];
      float v = vvn[j];
      float a0 = v * numw[c2] + numb[c2];         a0 = a0 > 0.f ? a0 : 0.f;
      float a1 = v * numw[c2 + 1] + numb[c2 + 1]; a1 = a1 > 0.f ? a1 : 0.f;
      x0 = a0 + pred[tp * D + c2];
      x1 = a1 + pred[tp * D + c2 + 1];
    }
    *(unsigned*)(ldso + SWZ(r, lane * 4)) = (unsigned)f2bf(x0) | ((unsigned)f2bf(x1) << 16);
  }
#pragma unroll
  for (int i = 0; i < 4; ++i) {
    int lr = i * 4 + g;
    int row = rbase + lr;
    if (row < nv)
      *(short8*)((char*)vars + (size_t)row * 256 + r16 * 16) =
          *(const short8*)(ldso + SWZ(lr, r16 * 16));
  }
  short8 a[4];
#pragma unroll
  for (int ks = 0; ks < 4; ++ks)
    a[ks] = *(const short8*)(ldso + SWZ(r16, ks * 64 + g * 16));
  for (int ct = 0; ct < 8; ++ct) {
    short8 b[4];
#pragma unroll
    for (int ks = 0; ks < 4; ++ks)
      b[ks] = *(const short8*)(WxT + (ct * 16 + r16) * D + ks * 32 + g * 8);
    f32x4 acc = {0.f, 0.f, 0.f, 0.f};
#pragma unroll
    for (int ks = 0; ks < 4; ++ks) acc = mfma16(a[ks], b[ks], acc);
#pragma unroll
    for (int j = 0; j < 4; ++j) {
      int lr = g * 4 + j;
      *(unsigned short*)(ldsa + SWZ(lr, (ct * 16 + r16) * 2)) = f2bf(acc[j]);
    }
  }
#pragma unroll
  for (int i = 0; i < 4; ++i) {
    int lr = i * 4 + g;
    int row = rbase + lr;
    if (row < nv)
      *(short8*)((char*)xw + (size_t)row * 256 + r16 * 16) =
          *(const short8*)(ldsa + SWZ(lr, r16 * 16));
  }
}

// ---------------- CSR gather-reduce with next-dest prefetch ----------------
__global__ void __launch_bounds__(256)
k_agg(const unsigned short* __restrict__ xW, const unsigned* __restrict__ pk,
      const int* __restrict__ off, const float* __restrict__ eW,
      unsigned short* __restrict__ agg, int nDest) {
  int lane = threadIdx.x & 63;
  int c2 = lane * 2;
  int gw = (blockIdx.x * blockDim.x + threadIdx.x) >> 6;
  int nW = (gridDim.x * blockDim.x) >> 6;
  float e00 = eW[c2], e01 = eW[c2 + 1];
  float e10 = eW[D + c2], e11 = eW[D + c2 + 1];
  float e20 = eW[2 * D + c2], e21 = eW[2 * D + c2 + 1];

  int d = gw;
  int b = 0, e = 0;
  if (d < nDest) { b = off[d]; e = off[d + 1]; }
  while (d < nDest) {
    int dn = d + nW;
    int bn = 0, en = 0;
    if (dn < nDest) { bn = off[dn]; en = off[dn + 1]; }  // prefetched under current bin
    float a0 = 0.f, a1 = 0.f;
    int i = b;
    for (; i + 4 <= e; i += 4) {
      unsigned p0 = pk[i], p1 = pk[i + 1], p2 = pk[i + 2], p3 = pk[i + 3];
      unsigned w0 = *(const unsigned*)(xW + (size_t)(p0 & 0xFFFFF) * D + c2);
      unsigned w1 = *(const unsigned*)(xW + (size_t)(p1 & 0xFFFFF) * D + c2);
      unsigned w2 = *(const unsigned*)(xW + (size_t)(p2 & 0xFFFFF) * D + c2);
      unsigned w3 = *(const unsigned*)(xW + (size_t)(p3 & 0xFFFFF) * D + c2);
      accum_edge(w0, p0 >> 20, e00, e01, e10, e11, e20, e21, a0, a1);
      accum_edge(w1, p1 >> 20, e00, e01, e10, e11, e20, e21, a0, a1);
      accum_edge(w2, p2 >> 20, e00, e01, e10, e11, e20, e21, a0, a1);
      accum_edge(w3, p3 >> 20, e00, e01, e10, e11, e20, e21, a0, a1);
    }
    if (i + 2 <= e) {
      unsigned p0 = pk[i], p1 = pk[i + 1];
      unsigned w0 = *(const unsigned*)(xW + (size_t)(p0 & 0xFFFFF) * D + c2);
      unsigned w1 = *(const unsigned*)(xW + (size_t)(p1 & 0xFFFFF) * D + c2);
      accum_edge(w0, p0 >> 20, e00, e01, e10, e11, e20, e21, a0, a1);
      accum_edge(w1, p1 >> 20, e00, e01, e10, e11, e20, e21, a0, a1);
      i += 2;
    }
    if (i < e) {
      unsigned p0 = pk[i];
      unsigned w0 = *(const unsigned*)(xW + (size_t)(p0 & 0xFFFFF) * D + c2);
      accum_edge(w0, p0 >> 20, e00, e01, e10, e11, e20, e21, a0, a1);
    }
    *(unsigned*)(agg + (size_t)d * D + c2) = (unsigned)f2bf(a0) | ((unsigned)f2bf(a1) << 16);
    d = dn; b = bn; e = en;
  }
}

// ---------------- fused update GEMM + (xw | policy), block-cooperative LDS A-staging ----------------
// A (state||agg rows, 16 x 512B) is staged ONCE per chunk by the whole block
// (2 x 16B loads per wave, non-redundant) into a double-buffered, XOR-swizzled
// LDS tile; all 4 waves ds_read their fragments. T14 split: loads for chunk
// c+G are ISSUED at iteration top (registers), ds_written into the spare
// buffer AFTER the tail -> HBM latency hides under MFMA+tail. Barriers are
// lgkm-only so stage loads stay in flight.
// Previous design had each of the 4 waves redundantly loading the same rows
// (4x VMEM instructions, 16-row-scattered addresses) - the ~1.6 TB/s wall.
// aggb/xwOut may ALIAS: stage reads of chunk c+G precede tail writes of chunk
// c; chunk rows are block-exclusive.
// SRC: 0 = A-first-half from femb[fcls[row]], 1 = from `state`
// TAIL: 0 = xw tail ; 1 = policy head
// STORE: 1 = write state_new back; 0 = skip (dead store elimination)
template <int SRC, int TAIL, int STORE>
__global__ void __launch_bounds__(256)
k_updxw(const int* __restrict__ fcls, const unsigned short* __restrict__ fembB,
        unsigned short* __restrict__ state, const unsigned short* aggb,
        const unsigned short* __restrict__ WuT, const unsigned short* __restrict__ WxT,
        unsigned short* xwOut, const unsigned short* __restrict__ WpT,
        const float* __restrict__ bpol, const void* __restrict__ maskp,
        const int* __restrict__ flag, float* __restrict__ out, int nRows) {
  __shared__ char STG[2][16 * 512];        // 2 x 8KB staged A (state|agg), swizzled
  __shared__ unsigned short LDSO[16 * 128];
  int wid = threadIdx.x >> 6, lane = threadIdx.x & 63;
  int r16 = lane & 15, g = lane >> 4;
  int ct0 = wid * 2;
  char* ldso = (char*)LDSO;

  // B1 (update weights, K=256): loaded once per block
  short8 b1[2][8];
#pragma unroll
  for (int c2 = 0; c2 < 2; ++c2)
#pragma unroll
    for (int ks = 0; ks < 8; ++ks)
      b1[c2][ks] = *(const short8*)(WuT + ((ct0 + c2) * 16 + r16) * 256 + ks * 32 + g * 8);

  short8 b2[2][4];
  short8 bp[4];
  float bias = 0.f;
  int fl = 0;
  if (TAIL == 0) {
#pragma unroll
    for (int c2 = 0; c2 < 2; ++c2)
#pragma unroll
      for (int ks = 0; ks < 4; ++ks)
        b2[c2][ks] = *(const short8*)(WxT + ((ct0 + c2) * 16 + r16) * D + ks * 32 + g * 8);
  } else {
#pragma unroll
    for (int ks = 0; ks < 4; ++ks)
      bp[ks] = *(const short8*)(WpT + r16 * D + ks * 32 + g * 8);
    bias = bpol[r16];
    fl = *flag;
  }

  int nChunks = (nRows + 15) >> 4;

  // This thread's fixed staging slots: 2 x 16B covering rows 2wid,2wid+1 (j=0)
  // and 8+2wid,8+2wid+1 (j=1). (r,o): o in [0,512): [0,256)=state, [256,512)=agg.
  int p0 = wid * 1024 + lane * 16;
  int p1 = p0 + 4096;
  int sr0 = p0 >> 9, so0 = p0 & 511;
  int sr1 = p1 >> 9, so1 = p1 & 511;
  // swizzled LDS byte offsets (fixed per thread)
  int ld0 = sr0 * 512 + (so0 < 256 ? (so0 ^ ((sr0 & 7) << 4))
                                   : 256 + (((so0 - 256) ^ ((sr0 & 7) << 4))));
  int ld1 = sr1 * 512 + (so1 < 256 ? (so1 ^ ((sr1 & 7) << 4))
                                   : 256 + (((so1 - 256) ^ ((sr1 & 7) << 4))));

  auto srcAddr = [&](int cc, int r, int o) -> const unsigned short* {
    int grow = cc * 16 + r;
    int arg = grow < nRows ? grow : nRows - 1;
    if (o < 256) {
      if (SRC == 0) return fembB + (size_t)fcls[arg] * D + (o >> 1);
      return state + (size_t)arg * D + (o >> 1);
    }
    return aggb + (size_t)arg * D + ((o - 256) >> 1);
  };

  int c = blockIdx.x;
  int cur = 0;
  if (c < nChunks) {
    short8 s0 = *(const short8*)srcAddr(c, sr0, so0);
    short8 s1 = *(const short8*)srcAddr(c, sr1, so1);
    *(short8*)(STG[0] + ld0) = s0;
    *(short8*)(STG[0] + ld1) = s1;
    wave_barrier_lds();
  }

  int swz = (r16 & 7) << 4;
  for (; c < nChunks; c += gridDim.x) {
    int cn = c + gridDim.x;
    short8 sn0, sn1;
    bool havenext = (cn < nChunks);
    if (havenext) {                    // T14: issue loads early (no wait here)
      sn0 = *(const short8*)srcAddr(cn, sr0, so0);
      sn1 = *(const short8*)srcAddr(cn, sr1, so1);
    }

    const char* stg = STG[cur];
    short8 a[8];
#pragma unroll
    for (int ks = 0; ks < 4; ++ks)
      a[ks] = *(const short8*)(stg + r16 * 512 + ((ks * 64 + g * 16) ^ swz));
#pragma unroll
    for (int ks = 0; ks < 4; ++ks)
      a[4 + ks] = *(const short8*)(stg + r16 * 512 + 256 + ((ks * 64 + g * 16) ^ swz));

    int rbase = c * 16;
    f32x4 acc0 = {0.f, 0.f, 0.f, 0.f}, acc1 = {0.f, 0.f, 0.f, 0.f};
#pragma unroll
    for (int ks = 0; ks < 8; ++ks) {
      acc0 = mfma16(a[ks], b1[0][ks], acc0);
      acc1 = mfma16(a[ks], b1[1][ks], acc1);
    }
#pragma unroll
    for (int j = 0; j < 4; ++j) {
      int lr = g * 4 + j;
      float v0 = acc0[j] > 0.f ? acc0[j] : 0.f;
      float v1 = acc1[j] > 0.f ? acc1[j] : 0.f;
      *(unsigned short*)(ldso + SWZ(lr, (ct0 * 16 + r16) * 2)) = f2bf(v0);
      *(unsigned short*)(ldso + SWZ(lr, ((ct0 + 1) * 16 + r16) * 2)) = f2bf(v1);
    }
    wave_barrier_lds();  // LDSO ready; all waves done reading STG[cur]

    if (TAIL == 0) {
      if (STORE) {
#pragma unroll
        for (int i = 0; i < 4; ++i) {
          int lr = i * 4 + g;
          int row = rbase + lr;
          if (row < nRows)
            *(short8*)((char*)state + (size_t)row * 256 + r16 * 16) =
                *(const short8*)(ldso + SWZ(lr, r16 * 16));
        }
      }
      // xw = state_new @ WxT (K=128)
      short8 a2[4];
#pragma unroll
      for (int ks = 0; ks < 4; ++ks)
        a2[ks] = *(const short8*)(ldso + SWZ(r16, ks * 64 + g * 16));
      f32x4 x0 = {0.f, 0.f, 0.f, 0.f}, x1 = {0.f, 0.f, 0.f, 0.f};
#pragma unroll
      for (int ks = 0; ks < 4; ++ks) {
        x0 = mfma16(a2[ks], b2[0][ks], x0);
        x1 = mfma16(a2[ks], b2[1][ks], x1);
      }
#pragma unroll
      for (int j = 0; j < 4; ++j) {
        int row = rbase + g * 4 + j;
        if (row < nRows) {
          xwOut[(size_t)row * D + ct0 * 16 + r16] = f2bf(x0[j]);
          xwOut[(size_t)row * D + (ct0 + 1) * 16 + r16] = f2bf(x1[j]);
        }
      }
    } else {
      if (wid == 0) {
        short8 a2[4];
#pragma unroll
        for (int ks = 0; ks < 4; ++ks)
          a2[ks] = *(const short8*)(ldso + SWZ(r16, ks * 64 + g * 16));
        f32x4 acc = {0.f, 0.f, 0.f, 0.f};
#pragma unroll
        for (int ks = 0; ks < 4; ++ks) acc = mfma16(a2[ks], bp[ks], acc);
#pragma unroll
        for (int j = 0; j < 4; ++j) {
          int grow = rbase + g * 4 + j;
          if (grow < nRows) {
            int mi = grow * NACT + r16;
            bool mv;
            if (fl & 2)      mv = ((const float*)maskp)[mi] != 0.0f;
            else if (fl & 1) mv = ((const unsigned char*)maskp)[mi] != 0;
            else             mv = ((const int*)maskp)[mi] != 0;
            out[mi] = mv ? (acc[j] + bias) : -1e9f;
          }
        }
      }
    }

    if (havenext) {                    // T14: write late into the spare buffer
      *(short8*)(STG[cur ^ 1] + ld0) = sn0;
      *(short8*)(STG[cur ^ 1] + ld1) = sn1;
    }
    wave_barrier_lds();  // LDSO protected; STG[cur^1] complete for next iter
    cur ^= 1;
  }
}

extern "C" void kernel_launch(void* const* d_in, const int* in_sizes, int n_in,
                              void* d_out, int out_size, void* d_ws, size_t ws_size,
                              hipStream_t stream) {
  const int*   vtb  = (const int*)d_in[0];
  const int*   vvb  = (const int*)d_in[1];
  const int*   vtn  = (const int*)d_in[2];
  const float* vvn  = (const float*)d_in[3];
  const int*   fcls = (const int*)d_in[4];
  const int*   sb   = (const int*)d_in[5];
  const int*   rb   = (const int*)d_in[6];
  const int*   tb   = (const int*)d_in[7];
  const int*   sn   = (const int*)d_in[8];
  const int*   rn   = (const int*)d_in[9];
  const int*   tn   = (const int*)d_in[10];
  const void*  mask = d_in[11];
  const float* pred = (const float*)d_in[12];
  const float* bemb = (const float*)d_in[13];
  const float* femb = (const float*)d_in[14];
  const float* eemb = (const float*)d_in[15];
  const float* numw = (const float*)d_in[16];
  const float* numb = (const float*)d_in[17];
  const float* Wvf  = (const float*)d_in[18];
  const float* Wuf  = (const float*)d_in[19];
  const float* Wfv  = (const float*)d_in[20];
  const float* Wuv  = (const float*)d_in[21];
  const float* Wpol = (const float*)d_in[22];
  const float* bpol = (const float*)d_in[23];

  int NVB = in_sizes[0], NVN = in_sizes[2], NF = in_sizes[4];
  int EB = in_sizes[5], EN = in_sizes[8];
  int NV = NVB + NVN, E = EB + EN;
  int nFemb = in_sizes[14];

  char* ws = (char*)d_ws;
  size_t off_b = 0;
  auto alloc = [&](size_t bytes) -> char* {
    char* p = ws + off_b;
    off_b = (off_b + bytes + 255) & ~(size_t)255;
    return p;
  };
  // Workspace budget: keep total under ~220 MB (313 MB aborted in R4/5).
  unsigned short* vars  = (unsigned short*)alloc((size_t)NV * D * 2);   // 76.8 MB
  unsigned short* facs  = (unsigned short*)alloc((size_t)NF * D * 2);   // 25.6 MB
  unsigned short* bufV  = (unsigned short*)alloc((size_t)NV * D * 2);   // 76.8 MB (xWv ≡ aggV)
  unsigned short* bufF  = (unsigned short*)alloc((size_t)NF * D * 2);   // 25.6 MB (xWf ≡ aggF)
  unsigned*       pkR   = (unsigned*)alloc((size_t)E * 4);
  unsigned*       pkS   = (unsigned*)alloc((size_t)E * 4);
  int*            offR  = (int*)alloc((size_t)(NF + 2) * 4);
  int*            offS  = (int*)alloc((size_t)(NV + 2) * 4);
  int*            bsum  = (int*)alloc(256 * 4);
  unsigned short* WvfT  = (unsigned short*)alloc((size_t)LAYERS * D * D * 2);
  unsigned short* WfvT  = (unsigned short*)alloc((size_t)LAYERS * D * D * 2);
  unsigned short* WufT  = (unsigned short*)alloc((size_t)LAYERS * D * 2 * D * 2);
  unsigned short* WuvT  = (unsigned short*)alloc((size_t)LAYERS * D * 2 * D * 2);
  unsigned short* WpT   = (unsigned short*)alloc((size_t)NACT * D * 2);
  unsigned short* fembB = (unsigned short*)alloc((size_t)nFemb * 2);
  float*          eWt   = (float*)alloc((size_t)LAYERS * 2 * 3 * D * 4);
  int*            flag  = (int*)alloc(256);

  // ---- setup ----
  hipMemsetAsync(flag, 0, 4, stream);
  k_detect<<<256, 256, 0, stream>>>((const unsigned int*)mask, NF * NACT / 4, flag);
  k_pack<<<64, 256, 0, stream>>>(Wvf, WvfT, LAYERS, D, D);
  k_pack<<<64, 256, 0, stream>>>(Wfv, WfvT, LAYERS, D, D);
  k_pack<<<96, 256, 0, stream>>>(Wuf, WufT, LAYERS, 2 * D, D);
  k_pack<<<96, 256, 0, stream>>>(Wuv, WuvT, LAYERS, 2 * D, D);
  k_pack<<<8, 256, 0, stream>>>(Wpol, WpT, 1, D, NACT);
  k_packrm<<<32, 256, 0, stream>>>(femb, fembB, nFemb);
  k_ew<<<(LAYERS * 2 * 3 * D + 255) / 256, 256, 0, stream>>>(eemb, Wvf, Wfv, eWt);

  // ---- CSR by receiver (bins = factors) ----
  int nbR = (NF + SCH - 1) / SCH;
  hipMemsetAsync(offR, 0, (size_t)(NF + 1) * 4, stream);
  k_hist<<<2048, 256, 0, stream>>>(rb, EB, 0, offR);
  k_hist<<<2048, 256, 0, stream>>>(rn, EN, 0, offR);
  k_scan_sums<<<nbR, 256, 0, stream>>>(offR, NF, bsum);
  k_scan_top<<<1, 64, 0, stream>>>(bsum, nbR);
  k_scan_apply<<<nbR, 256, 0, stream>>>(offR, NF, bsum);
  k_set1<<<1, 64, 0, stream>>>(offR + NF, E);
  k_scatter<<<2048, 256, 0, stream>>>(rb, sb, tb, EB, 0, 0, offR, pkR);
  k_scatter<<<2048, 256, 0, stream>>>(rn, sn, tn, EN, 0, NVB, offR, pkR);

  // ---- CSR by sender (bins = variables) ----
  int nbS = (NV + SCH - 1) / SCH;
  hipMemsetAsync(offS, 0, (size_t)(NV + 1) * 4, stream);
  k_hist<<<2048, 256, 0, stream>>>(sb, EB, 0, offS);
  k_hist<<<2048, 256, 0, stream>>>(sn, EN, NVB, offS);
  k_scan_sums<<<nbS, 256, 0, stream>>>(offS, NV, bsum);
  k_scan_top<<<1, 64, 0, stream>>>(bsum, nbS);
  k_scan_apply<<<nbS, 256, 0, stream>>>(offS, NV, bsum);
  k_set1<<<1, 64, 0, stream>>>(offS + NV, E);
  k_scatter<<<2048, 256, 0, stream>>>(sb, rb, tb, EB, 0, 0, offS, pkS);
  k_scatter<<<2048, 256, 0, stream>>>(sn, rn, tn, EN, NVB, 0, offS, pkS);

  // ---- fused embedding + xW_v(0) ----
  int gV = (NV + 63) / 64;
  k_emb_xw<<<gV, 256, 0, stream>>>(vtb, vvb, vtn, vvn, pred, bemb, numw, numb,
                                   WvfT, vars, bufV, NVB, NV);

  int gUV = 4096;   // NV: 18750 chunks -> ~4.6/block (pipeline engages)
  int gUF = 2048;   // NF:  6250 chunks -> ~3.0/block

  // ---- layer 0 ----
  k_agg<<<8192, 256, 0, stream>>>(bufV, pkR, offR, eWt + (size_t)(0 * 2 + 0) * 3 * D, bufF, NF);
  k_updxw<0, 0, 1><<<gUF, 256, 0, stream>>>(fcls, fembB, facs, bufF,
                                            WufT + (size_t)0 * D * 2 * D, WfvT + (size_t)0 * D * D,
                                            bufF, WpT, bpol, mask, flag, (float*)d_out, NF);
  k_agg<<<8192, 256, 0, stream>>>(bufF, pkS, offS, eWt + (size_t)(0 * 2 + 1) * 3 * D, bufV, NV);
  k_updxw<1, 0, 1><<<gUV, 256, 0, stream>>>(nullptr, nullptr, vars, bufV,
                                            WuvT + (size_t)0 * D * 2 * D, WvfT + (size_t)1 * D * D,
                                            bufV, WpT, bpol, mask, flag, (float*)d_out, NV);
  // ---- layer 1 ----
  k_agg<<<8192, 256, 0, stream>>>(bufV, pkR, offR, eWt + (size_t)(1 * 2 + 0) * 3 * D, bufF, NF);
  k_updxw<1, 0, 1><<<gUF, 256, 0, stream>>>(nullptr, nullptr, facs, bufF,
                                            WufT + (size_t)1 * D * 2 * D, WfvT + (size_t)1 * D * D,
                                            bufF, WpT, bpol, mask, flag, (float*)d_out, NF);
  k_agg<<<8192, 256, 0, stream>>>(bufF, pkS, offS, eWt + (size_t)(1 * 2 + 1) * 3 * D, bufV, NV);
  // vars state is never read after this update -> skip the 77MB dead store
  k_updxw<1, 0, 0><<<gUV, 256, 0, stream>>>(nullptr, nullptr, vars, bufV,
                                            WuvT + (size_t)1 * D * 2 * D, WvfT + (size_t)2 * D * D,
                                            bufV, WpT, bpol, mask, flag, (float*)d_out, NV);
  // ---- layer 2: factor update + policy (f->v pass not needed) ----
  k_agg<<<8192, 256, 0, stream>>>(bufV, pkR, offR, eWt + (size_t)(2 * 2 + 0) * 3 * D, bufF, NF);
  k_updxw<1, 1, 0><<<gUF, 256, 0, stream>>>(nullptr, nullptr, facs, bufF,
                                            WufT + (size_t)2 * D * 2 * D, nullptr,
                                            nullptr, WpT, bpol, mask, flag, (float*)d_out, NF);
}

// Round 14
// 767.731 us; speedup vs baseline: 1.0700x; 1.0700x over previous
//
#include <hip/hip_runtime.h>
#include <stdint.h>

#define D 128
#define NACT 16
#define LAYERS 3
#define SCH 8192

typedef __attribute__((ext_vector_type(4))) float f32x4;
typedef __attribute__((ext_vector_type(8))) short short8;

__device__ __forceinline__ unsigned short f2bf(float f) {
  union { float f; unsigned int u; } v; v.f = f;
  return (unsigned short)((v.u + 0x7fffu + ((v.u >> 16) & 1u)) >> 16);
}
__device__ __forceinline__ float bf2f(unsigned short s) {
  union { unsigned int u; float f; } v; v.u = ((unsigned int)s) << 16; return v.f;
}
__device__ __forceinline__ f32x4 mfma16(short8 a, short8 b, f32x4 c) {
  return __builtin_amdgcn_mfma_f32_16x16x32_bf16(a, b, c, 0, 0, 0);
}
// XOR swizzle: byte offset within a 16-row x 256B LDS tile
__device__ __forceinline__ int SWZ(int row, int byteoff) {
  return (row * 256 + byteoff) ^ ((row & 7) << 4);
}

// Barrier that does NOT drain vmcnt (lgkm-only): keeps T14 stage loads in
// flight across the barrier. sched_barrier(0) fences compiler reordering.
__device__ __forceinline__ void wave_barrier_lds() {
  asm volatile("s_waitcnt lgkmcnt(0)" ::: "memory");
  __builtin_amdgcn_s_barrier();
  __builtin_amdgcn_sched_barrier(0);
}

__device__ __forceinline__ void accum_edge(unsigned w, unsigned t,
                                           float e00, float e01, float e10, float e11,
                                           float e20, float e21, float& a0, float& a1) {
  float ee0 = (t == 0) ? e00 : ((t == 1) ? e10 : e20);
  float ee1 = (t == 0) ? e01 : ((t == 1) ? e11 : e21);
  float v0 = bf2f((unsigned short)(w & 0xFFFF)) + ee0;
  float v1 = bf2f((unsigned short)(w >> 16)) + ee1;
  a0 += v0 > 0.f ? v0 : 0.f;
  a1 += v1 > 0.f ? v1 : 0.f;
}

// ---------------- merged setup: weight packs + eW + femb + mask detect ----------------
__global__ void k_setup(const float* __restrict__ Wvf, const float* __restrict__ Wfv,
                        const float* __restrict__ Wuf, const float* __restrict__ Wuv,
                        const float* __restrict__ Wpol, const float* __restrict__ femb,
                        const float* __restrict__ eemb,
                        const unsigned int* __restrict__ mask, int nMaskWords, int nFemb,
                        unsigned short* __restrict__ WvfT, unsigned short* __restrict__ WfvT,
                        unsigned short* __restrict__ WufT, unsigned short* __restrict__ WuvT,
                        unsigned short* __restrict__ WpT, unsigned short* __restrict__ fembB,
                        float* __restrict__ eWt, int* __restrict__ flag) {
  int tid = blockIdx.x * blockDim.x + threadIdx.x;
  int nthr = gridDim.x * blockDim.x;
  auto packT = [&](const float* src, unsigned short* dst, int Lc, int K, int N) {
    int total = Lc * K * N;
    for (int i = tid; i < total; i += nthr) {
      int l = i / (K * N);
      int rem = i - l * (K * N);
      int n = rem / K;
      int k = rem - n * K;
      dst[i] = f2bf(src[(l * K + k) * N + n]);
    }
  };
  packT(Wvf, WvfT, LAYERS, D, D);
  packT(Wfv, WfvT, LAYERS, D, D);
  packT(Wuf, WufT, LAYERS, 2 * D, D);
  packT(Wuv, WuvT, LAYERS, 2 * D, D);
  packT(Wpol, WpT, 1, D, NACT);
  for (int i = tid; i < nFemb; i += nthr) fembB[i] = f2bf(femb[i]);
  for (int o = tid; o < LAYERS * 2 * 3 * D; o += nthr) {
    int c = o & 127;
    int r = o >> 7;
    int t = r % 3; r /= 3;
    int dir = r & 1;
    int l = r >> 1;
    const float* W = (dir == 0 ? Wvf : Wfv) + (size_t)l * D * D;
    float s = 0.f;
    for (int k = 0; k < D; ++k) s += eemb[t * D + k] * W[k * D + c];
    eWt[o] = s;
  }
  int f = 0;
  for (int i = tid; i < nMaskWords; i += nthr) {
    unsigned w = mask[i];
    if (w > 1u) f |= 1;
    if (w > 0x01010101u) f |= 2;
  }
  if (f) atomicOr(flag, f);
}

// ---------------- merged CSR build ----------------
__global__ void k_hist2(const int* __restrict__ rb, const int* __restrict__ rn,
                        const int* __restrict__ sb, const int* __restrict__ sn,
                        int EB, int EN, int NVB,
                        int* __restrict__ offR, int* __restrict__ offS) {
  int E = EB + EN;
  for (int e = blockIdx.x * blockDim.x + threadIdx.x; e < E; e += gridDim.x * blockDim.x) {
    int dR = (e < EB) ? rb[e] : rn[e - EB];
    atomicAdd(&offR[dR], 1);
    int dS = (e < EB) ? sb[e] : sn[e - EB] + NVB;
    atomicAdd(&offS[dS], 1);
  }
}

__global__ void k_scan_sums2(const int* __restrict__ offR, int nR, int* __restrict__ bsumR,
                             const int* __restrict__ offS, int nS, int* __restrict__ bsumS,
                             int nbR) {
  __shared__ int ts[256];
  const int* data; int n; int* bsum; int blk;
  if ((int)blockIdx.x < nbR) { data = offR; n = nR; bsum = bsumR; blk = blockIdx.x; }
  else { data = offS; n = nS; bsum = bsumS; blk = blockIdx.x - nbR; }
  int base = blk * SCH;
  int s = 0;
  for (int j = threadIdx.x; j < SCH; j += 256) {
    int i = base + j;
    if (i < n) s += data[i];
  }
  ts[threadIdx.x] = s;
  __syncthreads();
  if (threadIdx.x == 0) {
    int tot = 0;
    for (int i = 0; i < 256; ++i) tot += ts[i];
    bsum[blk] = tot;
  }
}

__global__ void k_scan_top2(int* __restrict__ bsumR, int nbR, int* __restrict__ offRend,
                            int* __restrict__ bsumS, int nbS, int* __restrict__ offSend,
                            int E) {
  if (threadIdx.x == 0) {
    int* bsum = (blockIdx.x == 0) ? bsumR : bsumS;
    int nb = (blockIdx.x == 0) ? nbR : nbS;
    int run = 0;
    for (int i = 0; i < nb; ++i) { int t = bsum[i]; bsum[i] = run; run += t; }
    if (blockIdx.x == 0) *offRend = E; else *offSend = E;
  }
}

__global__ void k_scan_apply2(int* __restrict__ offR, int nR, const int* __restrict__ bsumR,
                              int* __restrict__ offS, int nS, const int* __restrict__ bsumS,
                              int nbR) {
  __shared__ int ts[256];
  int* data; int n; const int* bsum; int blk;
  if ((int)blockIdx.x < nbR) { data = offR; n = nR; bsum = bsumR; blk = blockIdx.x; }
  else { data = offS; n = nS; bsum = bsumS; blk = blockIdx.x - nbR; }
  int base = blk * SCH + threadIdx.x * 32;
  int v[32];
  int s = 0;
#pragma unroll
  for (int j = 0; j < 32; ++j) {
    int i = base + j;
    v[j] = (i < n) ? data[i] : 0;
    s += v[j];
  }
  ts[threadIdx.x] = s;
  __syncthreads();
  if (threadIdx.x == 0) {
    int run = 0;
    for (int i = 0; i < 256; ++i) { int t = ts[i]; ts[i] = run; run += t; }
  }
  __syncthreads();
  int run = bsum[blk] + ts[threadIdx.x];
#pragma unroll
  for (int j = 0; j < 32; ++j) {
    run += v[j];
    int i = base + j;
    if (i < n) data[i] = run;  // inclusive scan
  }
}

__global__ void k_scatter2(const int* __restrict__ rb, const int* __restrict__ rn,
                           const int* __restrict__ sb, const int* __restrict__ sn,
                           const int* __restrict__ tb, const int* __restrict__ tn,
                           int EB, int EN, int NVB,
                           int* __restrict__ offR, unsigned* __restrict__ pkR,
                           int* __restrict__ offS, unsigned* __restrict__ pkS) {
  int E = EB + EN;
  for (int j = blockIdx.x * blockDim.x + threadIdx.x; j < 2 * E; j += gridDim.x * blockDim.x) {
    int d, s, t; int* off; unsigned* pk;
    if (j < E) {
      off = offR; pk = pkR;
      if (j < EB) { d = rb[j]; s = sb[j]; t = tb[j]; }
      else { int k = j - EB; d = rn[k]; s = sn[k] + NVB; t = tn[k]; }
    } else {
      int k2 = j - E;
      off = offS; pk = pkS;
      if (k2 < EB) { d = sb[k2]; s = rb[k2]; t = tb[k2]; }
      else { int k = k2 - EB; d = sn[k] + NVB; s = rn[k]; t = tn[k]; }
    }
    int pos = atomicAdd(&off[d], -1) - 1;
    pk[pos] = (unsigned)s | ((unsigned)t << 20);
  }
}

// ---------------- fused: variable embedding + xW_v(l=0), ILP-optimized ----------------
// Per-wave 16-row slice, no barriers. bemb/numw/numb hoisted to registers;
// 8-row index batches so pred gathers overlap; first B tile issued before the
// embedding; ct loop 1-deep B prefetch; xw results reuse the SAME LDS slice
// (embedding fully consumed into regs/vars before the first overwrite; LDS pipe
// is in-order per wave).
__global__ void __launch_bounds__(256)
k_emb_xw(const int* __restrict__ vtb, const int* __restrict__ vvb,
         const int* __restrict__ vtn, const float* __restrict__ vvn,
         const float* __restrict__ pred, const float* __restrict__ bemb,
         const float* __restrict__ numw, const float* __restrict__ numb,
         const unsigned short* __restrict__ WxT,
         unsigned short* __restrict__ vars, unsigned short* __restrict__ xw,
         int nvb, int nv) {
  __shared__ unsigned short LDSO[64 * 128];   // 16 KB; 4 KB per-wave slice
  int wid = threadIdx.x >> 6, lane = threadIdx.x & 63;
  int r16 = lane & 15, g = lane >> 4;
  int rbase = blockIdx.x * 64 + wid * 16;
  char* ldso = (char*)LDSO + wid * 16 * 256;
  int c2 = lane * 2;

  // per-lane constant columns (tiny tables, L1-resident)
  float be00 = bemb[c2],     be01 = bemb[c2 + 1];
  float be10 = bemb[D + c2], be11 = bemb[D + c2 + 1];
  float nw0 = numw[c2], nw1 = numw[c2 + 1];
  float nb0 = numb[c2], nb1 = numb[c2 + 1];

  // first B tile: issue early, consumed after embedding
  short8 bcur[4], bnxt[4];
#pragma unroll
  for (int ks = 0; ks < 4; ++ks)
    bcur[ks] = *(const short8*)(WxT + r16 * D + ks * 32 + g * 8);

  // embedding: two 8-row batches; index loads first (independent), then gathers
#pragma unroll
  for (int h = 0; h < 2; ++h) {
    int tpA[8], isb[8], bvA[8];
    float vlA[8];
#pragma unroll
    for (int r = 0; r < 8; ++r) {
      int row = rbase + h * 8 + r;
      int rg = row < nv ? row : nv - 1;
      isb[r] = rg < nvb;
      if (isb[r]) { tpA[r] = vtb[rg]; bvA[r] = vvb[rg]; vlA[r] = 0.f; }
      else        { tpA[r] = vtn[rg - nvb]; bvA[r] = 0; vlA[r] = vvn[rg - nvb]; }
    }
#pragma unroll
    for (int r = 0; r < 8; ++r) {
      float2 p = *(const float2*)(pred + (size_t)tpA[r] * D + c2);
      float x0, x1;
      if (isb[r]) {
        x0 = p.x + (bvA[r] ? be10 : be00);
        x1 = p.y + (bvA[r] ? be11 : be01);
      } else {
        float a0 = vlA[r] * nw0 + nb0; a0 = a0 > 0.f ? a0 : 0.f;
        float a1 = vlA[r] * nw1 + nb1; a1 = a1 > 0.f ? a1 : 0.f;
        x0 = p.x + a0;
        x1 = p.y + a1;
      }
      *(unsigned*)(ldso + SWZ(h * 8 + r, lane * 4)) =
          (unsigned)f2bf(x0) | ((unsigned)f2bf(x1) << 16);
    }
  }

  // vars store (coalesced 16B from LDS)
#pragma unroll
  for (int i = 0; i < 4; ++i) {
    int lr = i * 4 + g;
    int row = rbase + lr;
    if (row < nv)
      *(short8*)((char*)vars + (size_t)row * 256 + r16 * 16) =
          *(const short8*)(ldso + SWZ(lr, r16 * 16));
  }
  // A fragments (whole slice consumed into registers)
  short8 a[4];
#pragma unroll
  for (int ks = 0; ks < 4; ++ks)
    a[ks] = *(const short8*)(ldso + SWZ(r16, ks * 64 + g * 16));

  // xw GEMM: 1-deep B prefetch; results overwrite the same LDS slice
  for (int ct = 0; ct < 8; ++ct) {
    if (ct < 7) {
#pragma unroll
      for (int ks = 0; ks < 4; ++ks)
        bnxt[ks] = *(const short8*)(WxT + ((ct + 1) * 16 + r16) * D + ks * 32 + g * 8);
    }
    f32x4 acc = {0.f, 0.f, 0.f, 0.f};
#pragma unroll
    for (int ks = 0; ks < 4; ++ks) acc = mfma16(a[ks], bcur[ks], acc);
#pragma unroll
    for (int j = 0; j < 4; ++j) {
      int lr = g * 4 + j;
      *(unsigned short*)(ldso + SWZ(lr, (ct * 16 + r16) * 2)) = f2bf(acc[j]);
    }
#pragma unroll
    for (int ks = 0; ks < 4; ++ks) bcur[ks] = bnxt[ks];
  }
#pragma unroll
  for (int i = 0; i < 4; ++i) {
    int lr = i * 4 + g;
    int row = rbase + lr;
    if (row < nv)
      *(short8*)((char*)xw + (size_t)row * 256 + r16 * 16) =
          *(const short8*)(ldso + SWZ(lr, r16 * 16));
  }
}

// ---------------- CSR gather-reduce with next-dest prefetch ----------------
__global__ void __launch_bounds__(256)
k_agg(const unsigned short* __restrict__ xW, const unsigned* __restrict__ pk,
      const int* __restrict__ off, const float* __restrict__ eW,
      unsigned short* __restrict__ agg, int nDest) {
  int lane = threadIdx.x & 63;
  int c2 = lane * 2;
  int gw = (blockIdx.x * blockDim.x + threadIdx.x) >> 6;
  int nW = (gridDim.x * blockDim.x) >> 6;
  float e00 = eW[c2], e01 = eW[c2 + 1];
  float e10 = eW[D + c2], e11 = eW[D + c2 + 1];
  float e20 = eW[2 * D + c2], e21 = eW[2 * D + c2 + 1];

  int d = gw;
  int b = 0, e = 0;
  if (d < nDest) { b = off[d]; e = off[d + 1]; }
  while (d < nDest) {
    int dn = d + nW;
    int bn = 0, en = 0;
    if (dn < nDest) { bn = off[dn]; en = off[dn + 1]; }  // prefetched under current bin
    float a0 = 0.f, a1 = 0.f;
    int i = b;
    for (; i + 4 <= e; i += 4) {
      unsigned p0 = pk[i], p1 = pk[i + 1], p2 = pk[i + 2], p3 = pk[i + 3];
      unsigned w0 = *(const unsigned*)(xW + (size_t)(p0 & 0xFFFFF) * D + c2);
      unsigned w1 = *(const unsigned*)(xW + (size_t)(p1 & 0xFFFFF) * D + c2);
      unsigned w2 = *(const unsigned*)(xW + (size_t)(p2 & 0xFFFFF) * D + c2);
      unsigned w3 = *(const unsigned*)(xW + (size_t)(p3 & 0xFFFFF) * D + c2);
      accum_edge(w0, p0 >> 20, e00, e01, e10, e11, e20, e21, a0, a1);
      accum_edge(w1, p1 >> 20, e00, e01, e10, e11, e20, e21, a0, a1);
      accum_edge(w2, p2 >> 20, e00, e01, e10, e11, e20, e21, a0, a1);
      accum_edge(w3, p3 >> 20, e00, e01, e10, e11, e20, e21, a0, a1);
    }
    if (i + 2 <= e) {
      unsigned p0 = pk[i], p1 = pk[i + 1];
      unsigned w0 = *(const unsigned*)(xW + (size_t)(p0 & 0xFFFFF) * D + c2);
      unsigned w1 = *(const unsigned*)(xW + (size_t)(p1 & 0xFFFFF) * D + c2);
      accum_edge(w0, p0 >> 20, e00, e01, e10, e11, e20, e21, a0, a1);
      accum_edge(w1, p1 >> 20, e00, e01, e10, e11, e20, e21, a0, a1);
      i += 2;
    }
    if (i < e) {
      unsigned p0 = pk[i];
      unsigned w0 = *(const unsigned*)(xW + (size_t)(p0 & 0xFFFFF) * D + c2);
      accum_edge(w0, p0 >> 20, e00, e01, e10, e11, e20, e21, a0, a1);
    }
    *(unsigned*)(agg + (size_t)d * D + c2) = (unsigned)f2bf(a0) | ((unsigned)f2bf(a1) << 16);
    d = dn; b = bn; e = en;
  }
}

// ---------------- fused update GEMM + (xw | policy), block-cooperative LDS A-staging ----------------
// (unchanged from round 13 — proven: k_updxw dropped below top-5)
template <int SRC, int TAIL, int STORE>
__global__ void __launch_bounds__(256)
k_updxw(const int* __restrict__ fcls, const unsigned short* __restrict__ fembB,
        unsigned short* __restrict__ state, const unsigned short* aggb,
        const unsigned short* __restrict__ WuT, const unsigned short* __restrict__ WxT,
        unsigned short* xwOut, const unsigned short* __restrict__ WpT,
        const float* __restrict__ bpol, const void* __restrict__ maskp,
        const int* __restrict__ flag, float* __restrict__ out, int nRows) {
  __shared__ char STG[2][16 * 512];        // 2 x 8KB staged A (state|agg), swizzled
  __shared__ unsigned short LDSO[16 * 128];
  int wid = threadIdx.x >> 6, lane = threadIdx.x & 63;
  int r16 = lane & 15, g = lane >> 4;
  int ct0 = wid * 2;
  char* ldso = (char*)LDSO;

  short8 b1[2][8];
#pragma unroll
  for (int c2 = 0; c2 < 2; ++c2)
#pragma unroll
    for (int ks = 0; ks < 8; ++ks)
      b1[c2][ks] = *(const short8*)(WuT + ((ct0 + c2) * 16 + r16) * 256 + ks * 32 + g * 8);

  short8 b2[2][4];
  short8 bp[4];
  float bias = 0.f;
  int fl = 0;
  if (TAIL == 0) {
#pragma unroll
    for (int c2 = 0; c2 < 2; ++c2)
#pragma unroll
      for (int ks = 0; ks < 4; ++ks)
        b2[c2][ks] = *(const short8*)(WxT + ((ct0 + c2) * 16 + r16) * D + ks * 32 + g * 8);
  } else {
#pragma unroll
    for (int ks = 0; ks < 4; ++ks)
      bp[ks] = *(const short8*)(WpT + r16 * D + ks * 32 + g * 8);
    bias = bpol[r16];
    fl = *flag;
  }

  int nChunks = (nRows + 15) >> 4;

  int p0 = wid * 1024 + lane * 16;
  int p1 = p0 + 4096;
  int sr0 = p0 >> 9, so0 = p0 & 511;
  int sr1 = p1 >> 9, so1 = p1 & 511;
  int ld0 = sr0 * 512 + (so0 < 256 ? (so0 ^ ((sr0 & 7) << 4))
                                   : 256 + (((so0 - 256) ^ ((sr0 & 7) << 4))));
  int ld1 = sr1 * 512 + (so1 < 256 ? (so1 ^ ((sr1 & 7) << 4))
                                   : 256 + (((so1 - 256) ^ ((sr1 & 7) << 4))));

  auto srcAddr = [&](int cc, int r, int o) -> const unsigned short* {
    int grow = cc * 16 + r;
    int arg = grow < nRows ? grow : nRows - 1;
    if (o < 256) {
      if (SRC == 0) return fembB + (size_t)fcls[arg] * D + (o >> 1);
      return state + (size_t)arg * D + (o >> 1);
    }
    return aggb + (size_t)arg * D + ((o - 256) >> 1);
  };

  int c = blockIdx.x;
  int cur = 0;
  if (c < nChunks) {
    short8 s0 = *(const short8*)srcAddr(c, sr0, so0);
    short8 s1 = *(const short8*)srcAddr(c, sr1, so1);
    *(short8*)(STG[0] + ld0) = s0;
    *(short8*)(STG[0] + ld1) = s1;
    wave_barrier_lds();
  }

  int swz = (r16 & 7) << 4;
  for (; c < nChunks; c += gridDim.x) {
    int cn = c + gridDim.x;
    short8 sn0, sn1;
    bool havenext = (cn < nChunks);
    if (havenext) {                    // T14: issue loads early (no wait here)
      sn0 = *(const short8*)srcAddr(cn, sr0, so0);
      sn1 = *(const short8*)srcAddr(cn, sr1, so1);
    }

    const char* stg = STG[cur];
    short8 a[8];
#pragma unroll
    for (int ks = 0; ks < 4; ++ks)
      a[ks] = *(const short8*)(stg + r16 * 512 + ((ks * 64 + g * 16) ^ swz));
#pragma unroll
    for (int ks = 0; ks < 4; ++ks)
      a[4 + ks] = *(const short8*)(stg + r16 * 512 + 256 + ((ks * 64 + g * 16) ^ swz));

    int rbase = c * 16;
    f32x4 acc0 = {0.f, 0.f, 0.f, 0.f}, acc1 = {0.f, 0.f, 0.f, 0.f};
#pragma unroll
    for (int ks = 0; ks < 8; ++ks) {
      acc0 = mfma16(a[ks], b1[0][ks], acc0);
      acc1 = mfma16(a[ks], b1[1][ks], acc1);
    }
#pragma unroll
    for (int j = 0; j < 4; ++j) {
      int lr = g * 4 + j;
      float v0 = acc0[j] > 0.f ? acc0[j] : 0.f;
      float v1 = acc1[j] > 0.f ? acc1[j] : 0.f;
      *(unsigned short*)(ldso + SWZ(lr, (ct0 * 16 + r16) * 2)) = f2bf(v0);
      *(unsigned short*)(ldso + SWZ(lr, ((ct0 + 1) * 16 + r16) * 2)) = f2bf(v1);
    }
    wave_barrier_lds();  // LDSO ready; all waves done reading STG[cur]

    if (TAIL == 0) {
      if (STORE) {
#pragma unroll
        for (int i = 0; i < 4; ++i) {
          int lr = i * 4 + g;
          int row = rbase + lr;
          if (row < nRows)
            *(short8*)((char*)state + (size_t)row * 256 + r16 * 16) =
                *(const short8*)(ldso + SWZ(lr, r16 * 16));
        }
      }
      short8 a2[4];
#pragma unroll
      for (int ks = 0; ks < 4; ++ks)
        a2[ks] = *(const short8*)(ldso + SWZ(r16, ks * 64 + g * 16));
      f32x4 x0 = {0.f, 0.f, 0.f, 0.f}, x1 = {0.f, 0.f, 0.f, 0.f};
#pragma unroll
      for (int ks = 0; ks < 4; ++ks) {
        x0 = mfma16(a2[ks], b2[0][ks], x0);
        x1 = mfma16(a2[ks], b2[1][ks], x1);
      }
#pragma unroll
      for (int j = 0; j < 4; ++j) {
        int row = rbase + g * 4 + j;
        if (row < nRows) {
          xwOut[(size_t)row * D + ct0 * 16 + r16] = f2bf(x0[j]);
          xwOut[(size_t)row * D + (ct0 + 1) * 16 + r16] = f2bf(x1[j]);
        }
      }
    } else {
      if (wid == 0) {
        short8 a2[4];
#pragma unroll
        for (int ks = 0; ks < 4; ++ks)
          a2[ks] = *(const short8*)(ldso + SWZ(r16, ks * 64 + g * 16));
        f32x4 acc = {0.f, 0.f, 0.f, 0.f};
#pragma unroll
        for (int ks = 0; ks < 4; ++ks) acc = mfma16(a2[ks], bp[ks], acc);
#pragma unroll
        for (int j = 0; j < 4; ++j) {
          int grow = rbase + g * 4 + j;
          if (grow < nRows) {
            int mi = grow * NACT + r16;
            bool mv;
            if (fl & 2)      mv = ((const float*)maskp)[mi] != 0.0f;
            else if (fl & 1) mv = ((const unsigned char*)maskp)[mi] != 0;
            else             mv = ((const int*)maskp)[mi] != 0;
            out[mi] = mv ? (acc[j] + bias) : -1e9f;
          }
        }
      }
    }

    if (havenext) {                    // T14: write late into the spare buffer
      *(short8*)(STG[cur ^ 1] + ld0) = sn0;
      *(short8*)(STG[cur ^ 1] + ld1) = sn1;
    }
    wave_barrier_lds();  // LDSO protected; STG[cur^1] complete for next iter
    cur ^= 1;
  }
}

extern "C" void kernel_launch(void* const* d_in, const int* in_sizes, int n_in,
                              void* d_out, int out_size, void* d_ws, size_t ws_size,
                              hipStream_t stream) {
  const int*   vtb  = (const int*)d_in[0];
  const int*   vvb  = (const int*)d_in[1];
  const int*   vtn  = (const int*)d_in[2];
  const float* vvn  = (const float*)d_in[3];
  const int*   fcls = (const int*)d_in[4];
  const int*   sb   = (const int*)d_in[5];
  const int*   rb   = (const int*)d_in[6];
  const int*   tb   = (const int*)d_in[7];
  const int*   sn   = (const int*)d_in[8];
  const int*   rn   = (const int*)d_in[9];
  const int*   tn   = (const int*)d_in[10];
  const void*  mask = d_in[11];
  const float* pred = (const float*)d_in[12];
  const float* bemb = (const float*)d_in[13];
  const float* femb = (const float*)d_in[14];
  const float* eemb = (const float*)d_in[15];
  const float* numw = (const float*)d_in[16];
  const float* numb = (const float*)d_in[17];
  const float* Wvf  = (const float*)d_in[18];
  const float* Wuf  = (const float*)d_in[19];
  const float* Wfv  = (const float*)d_in[20];
  const float* Wuv  = (const float*)d_in[21];
  const float* Wpol = (const float*)d_in[22];
  const float* bpol = (const float*)d_in[23];

  int NVB = in_sizes[0], NVN = in_sizes[2], NF = in_sizes[4];
  int EB = in_sizes[5], EN = in_sizes[8];
  int NV = NVB + NVN, E = EB + EN;
  int nFemb = in_sizes[14];

  char* ws = (char*)d_ws;
  size_t off_b = 0;
  auto alloc = [&](size_t bytes) -> char* {
    char* p = ws + off_b;
    off_b = (off_b + bytes + 255) & ~(size_t)255;
    return p;
  };
  // Workspace budget: keep total under ~220 MB (313 MB aborted in R4/5).
  unsigned short* vars  = (unsigned short*)alloc((size_t)NV * D * 2);   // 76.8 MB
  unsigned short* facs  = (unsigned short*)alloc((size_t)NF * D * 2);   // 25.6 MB
  unsigned short* bufV  = (unsigned short*)alloc((size_t)NV * D * 2);   // 76.8 MB (xWv ≡ aggV)
  unsigned short* bufF  = (unsigned short*)alloc((size_t)NF * D * 2);   // 25.6 MB (xWf ≡ aggF)
  unsigned*       pkR   = (unsigned*)alloc((size_t)E * 4);
  unsigned*       pkS   = (unsigned*)alloc((size_t)E * 4);
  int*            offR  = (int*)alloc((size_t)(NF + 2) * 4);
  int*            offS  = (int*)alloc((size_t)(NV + 2) * 4);
  int*            bsumR = (int*)alloc(256 * 4);
  int*            bsumS = (int*)alloc(256 * 4);
  unsigned short* WvfT  = (unsigned short*)alloc((size_t)LAYERS * D * D * 2);
  unsigned short* WfvT  = (unsigned short*)alloc((size_t)LAYERS * D * D * 2);
  unsigned short* WufT  = (unsigned short*)alloc((size_t)LAYERS * D * 2 * D * 2);
  unsigned short* WuvT  = (unsigned short*)alloc((size_t)LAYERS * D * 2 * D * 2);
  unsigned short* WpT   = (unsigned short*)alloc((size_t)NACT * D * 2);
  unsigned short* fembB = (unsigned short*)alloc((size_t)nFemb * 2);
  float*          eWt   = (float*)alloc((size_t)LAYERS * 2 * 3 * D * 4);
  int*            flag  = (int*)alloc(256);

  // ---- setup (merged) ----
  hipMemsetAsync(flag, 0, 4, stream);
  k_setup<<<512, 256, 0, stream>>>(Wvf, Wfv, Wuf, Wuv, Wpol, femb, eemb,
                                   (const unsigned int*)mask, NF * NACT / 4, nFemb,
                                   WvfT, WfvT, WufT, WuvT, WpT, fembB, eWt, flag);

  // ---- CSR build (merged) ----
  int nbR = (NF + SCH - 1) / SCH;
  int nbS = (NV + SCH - 1) / SCH;
  hipMemsetAsync(offR, 0, (size_t)(NF + 1) * 4, stream);
  hipMemsetAsync(offS, 0, (size_t)(NV + 1) * 4, stream);
  k_hist2<<<2048, 256, 0, stream>>>(rb, rn, sb, sn, EB, EN, NVB, offR, offS);
  k_scan_sums2<<<nbR + nbS, 256, 0, stream>>>(offR, NF, bsumR, offS, NV, bsumS, nbR);
  k_scan_top2<<<2, 64, 0, stream>>>(bsumR, nbR, offR + NF, bsumS, nbS, offS + NV, E);
  k_scan_apply2<<<nbR + nbS, 256, 0, stream>>>(offR, NF, bsumR, offS, NV, bsumS, nbR);
  k_scatter2<<<4096, 256, 0, stream>>>(rb, rn, sb, sn, tb, tn, EB, EN, NVB,
                                       offR, pkR, offS, pkS);

  // ---- fused embedding + xW_v(0) ----
  int gV = (NV + 63) / 64;
  k_emb_xw<<<gV, 256, 0, stream>>>(vtb, vvb, vtn, vvn, pred, bemb, numw, numb,
                                   WvfT, vars, bufV, NVB, NV);

  int gUV = 4096;   // NV: 18750 chunks -> ~4.6/block (pipeline engages)
  int gUF = 2048;   // NF:  6250 chunks -> ~3.0/block

  // ---- layer 0 ----
  k_agg<<<8192, 256, 0, stream>>>(bufV, pkR, offR, eWt + (size_t)(0 * 2 + 0) * 3 * D, bufF, NF);
  k_updxw<0, 0, 1><<<gUF, 256, 0, stream>>>(fcls, fembB, facs, bufF,
                                            WufT + (size_t)0 * D * 2 * D, WfvT + (size_t)0 * D * D,
                                            bufF, WpT, bpol, mask, flag, (float*)d_out, NF);
  k_agg<<<8192, 256, 0, stream>>>(bufF, pkS, offS, eWt + (size_t)(0 * 2 + 1) * 3 * D, bufV, NV);
  k_updxw<1, 0, 1><<<gUV, 256, 0, stream>>>(nullptr, nullptr, vars, bufV,
                                            WuvT + (size_t)0 * D * 2 * D, WvfT + (size_t)1 * D * D,
                                            bufV, WpT, bpol, mask, flag, (float*)d_out, NV);
  // ---- layer 1 ----
  k_agg<<<8192, 256, 0, stream>>>(bufV, pkR, offR, eWt + (size_t)(1 * 2 + 0) * 3 * D, bufF, NF);
  k_updxw<1, 0, 1><<<gUF, 256, 0, stream>>>(nullptr, nullptr, facs, bufF,
                                            WufT + (size_t)1 * D * 2 * D, WfvT + (size_t)1 * D * D,
                                            bufF, WpT, bpol, mask, flag, (float*)d_out, NF);
  k_agg<<<8192, 256, 0, stream>>>(bufF, pkS, offS, eWt + (size_t)(1 * 2 + 1) * 3 * D, bufV, NV);
  // vars state is never read after this update -> skip the 77MB dead store
  k_updxw<1, 0, 0><<<gUV, 256, 0, stream>>>(nullptr, nullptr, vars, bufV,
                                            WuvT + (size_t)1 * D * 2 * D, WvfT + (size_t)2 * D * D,
                                            bufV, WpT, bpol, mask, flag, (float*)d_out, NV);
  // ---- layer 2: factor update + policy (f->v pass not needed) ----
  k_agg<<<8192, 256, 0, stream>>>(bufV, pkR, offR, eWt + (size_t)(2 * 2 + 0) * 3 * D, bufF, NF);
  k_updxw<1, 1, 0><<<gUF, 256, 0, stream>>>(nullptr, nullptr, facs, bufF,
                                            WufT + (size_t)2 * D * 2 * D, nullptr,
                                            nullptr, WpT, bpol, mask, flag, (float*)d_out, NF);
}